// Round 14
// baseline (253.946 us; speedup 1.0000x reference)
//
#include <hip/hip_runtime.h>
#include <hip/hip_bf16.h>

// NT-Xent loss. N=4096 pairs, D=1024, 2N=8192 rows.
// loss = 1/T + mean_i log( sum_{j != i} exp(sim_ij - 1/T) ) - mean_i pos_i
// sim = Z Z^T (cosine); fixed max 1/T (cosine bound) -> no online max.
// R12: register-pipelined frags (k-paired Z, b128 reads, P/Q ping-pong).
// R13: counted vmcnt + merged tail -> null on vmcnt; isolated the real
//      bottleneck: 1 block/CU (96-128 KB LDS) -> block-wide barrier/wait
//      stalls have no co-resident block to fill them (m114 unavailable).
// R14: 256x128 cells, NB=3 x 24 KB = 72 KB -> 2 blocks/CU (144/160 KB).
//      R12 drain-0 pipeline verbatim (counted-vmcnt needs NB=4, worth ~0).
//      Packing: 992 main cells (bj >= 2bi+2) = 2 clean rounds of 512 slots;
//      96 quarter-work 128x128 band cells backfill round 2's 32 free slots.

#define NPAIR 4096
#define NROWS 8192
#define DIM   1024
#define NMAIN 992                   // 256x128 cells fully above diagonal
#define NTAIL 96                    // diag band: 32 d-blocks x 3 subcells
#define NKT   16                    // K-tiles of 64
#define INV_T 14.285714285714286f   // 1/0.07

typedef __attribute__((ext_vector_type(4))) float f32x4;
typedef __attribute__((ext_vector_type(2))) long  i64x2;

#define GLOAD_LDS16(g, l)                                              \
  __builtin_amdgcn_global_load_lds(                                    \
      (const __attribute__((address_space(1))) void*)(g),              \
      (__attribute__((address_space(3))) void*)(l), 16, 0, 0)

#define MFMA_FP8(A, B, C)                                              \
  __builtin_amdgcn_mfma_f32_16x16x32_fp8_fp8((long)(A), (long)(B), (C), 0, 0, 0)

#define WAIT_VM(N)  asm volatile("s_waitcnt vmcnt(" #N ")" ::: "memory")
#define BARRIER()   { __builtin_amdgcn_s_barrier();                    \
                      __builtin_amdgcn_sched_barrier(0); }

// ---------------------------------------------------------------------------
// Kernel A: per pair-row i: norms + cross dot (fp32); write fp8 e4m3
// normalized rows in k-PAIRED layout (16B chunk g = 8B of k-half0 ++ 8B of
// k-half1 within each 64-k tile); pos[i] = cos/T; zero rowsum (2/block).
// ---------------------------------------------------------------------------
__global__ __launch_bounds__(256) void normalize_kernel(
    const float* __restrict__ l1, const float* __restrict__ l2,
    unsigned char* __restrict__ Z, float* __restrict__ pos,
    float* __restrict__ rowsum) {
  const int i = blockIdx.x;
  const int t = threadIdx.x;           // one float4 per thread
  if (t < 2) rowsum[i * 2 + t] = 0.f;
  const float4 a = ((const float4*)(l1 + (size_t)i * DIM))[t];
  const float4 b = ((const float4*)(l2 + (size_t)i * DIM))[t];
  float s1 = a.x*a.x + a.y*a.y + a.z*a.z + a.w*a.w;
  float s2 = b.x*b.x + b.y*b.y + b.z*b.z + b.w*b.w;
  float d  = a.x*b.x + a.y*b.y + a.z*b.z + a.w*b.w;

  #pragma unroll
  for (int off = 32; off; off >>= 1) {
    s1 += __shfl_down(s1, off);
    s2 += __shfl_down(s2, off);
    d  += __shfl_down(d,  off);
  }
  __shared__ float red[3][4];
  __shared__ float fin[3];
  const int wave = t >> 6, lane = t & 63;
  if (lane == 0) { red[0][wave] = s1; red[1][wave] = s2; red[2][wave] = d; }
  __syncthreads();
  if (t == 0) {
    float S1 = red[0][0] + red[0][1] + red[0][2] + red[0][3];
    float S2 = red[1][0] + red[1][1] + red[1][2] + red[1][3];
    float DD = red[2][0] + red[2][1] + red[2][2] + red[2][3];
    float r1 = rsqrtf(S1), r2 = rsqrtf(S2);
    fin[0] = r1; fin[1] = r2;
    pos[i] = DD * r1 * r2 * INV_T;
  }
  __syncthreads();
  const float r1 = fin[0], r2 = fin[1];
  int pa = __builtin_amdgcn_cvt_pk_fp8_f32(a.x * r1, a.y * r1, 0, false);
  pa     = __builtin_amdgcn_cvt_pk_fp8_f32(a.z * r1, a.w * r1, pa, true);
  int pb = __builtin_amdgcn_cvt_pk_fp8_f32(b.x * r2, b.y * r2, 0, false);
  pb     = __builtin_amdgcn_cvt_pk_fp8_f32(b.z * r2, b.w * r2, pb, true);
  const int k0 = t * 4;
  const int noff = (k0 >> 6) * 64 + (((k0 >> 3) & 3) << 4)
                 + (((k0 >> 5) & 1) << 3) + (k0 & 7);
  *(int*)(Z + (size_t)i * DIM + noff) = pa;
  *(int*)(Z + (size_t)(i + NPAIR) * DIM + noff) = pb;
}

// ---------------------------------------------------------------------------
// Kernel B: single dispatch, 1088 blocks, 72 KB LDS -> 2 blocks/CU.
//  blocks [0,992): 256x128 cells fully above the diagonal (bj >= 2bi+2),
//    fp8, register-pipelined R12 loop (drain-0, NB=3).
//  blocks [992,1088): diag-band tail, 128x128 cells (upper-tri / full /
//    lower-tri; gcol>grow mask), 3-buffer pipeline (R13-verified).
// ---------------------------------------------------------------------------
__global__ __launch_bounds__(512, 4) void ntxent_gemm_all(
    const unsigned char* __restrict__ Z, float* __restrict__ rowsum) {
  __shared__ unsigned char lds[3 * 24576];   // main: 3 bufs x (A 16K + B 8K)

  const int t    = threadIdx.x;
  const int wid  = t >> 6;
  const int lane = t & 63;
  const int lrow = lane & 15;
  const int kgrp = lane >> 4;

  if (blockIdx.x < NMAIN) {
    // =========================== main path (256x128) =======================
    const int wm = wid >> 1;        // 0..3: 64-row quarter of 256 rows
    const int wn = wid & 1;         // 0..1: 64-col half of 128 cols

    // T1: bijective XCD swizzle (992 = 8*124) + decode (R8-verified):
    // cells before row-block bi: bi*(63-bi); bj = 2bi+2+rem.
    const int idx = (blockIdx.x & 7) * 124 + (blockIdx.x >> 3);
    int bi = (int)((63.0f - sqrtf(3969.0f - 4.0f * (float)idx)) * 0.5f);
    while ((bi + 1) * (62 - bi) <= idx) ++bi;
    while (bi * (63 - bi) > idx) --bi;
    const int bj = 2 * bi + 2 + (idx - bi * (63 - bi));
    const int brow = bi * 256, bcol = bj * 128;

    // Stage one K-tile: A 256x64 (2 gloads) + B 128x64 (1 gload).
    auto stage_tile = [&](int kt, int bufoff) {
      #pragma unroll
      for (int i = 0; i < 2; ++i) {
        const int cb = wid * 128 + i * 64;   // wave-uniform chunk base
        const int c  = cb + lane;
        const int r  = c >> 2;
        const int lc = (c & 3) ^ ((r >> 1) & 3);
        GLOAD_LDS16(Z + (size_t)(brow + r) * DIM + kt * 64 + lc * 16,
                    lds + bufoff + cb * 16);
      }
      {
        const int cb = wid * 64;
        const int c  = cb + lane;
        const int r  = c >> 2;
        const int lc = (c & 3) ^ ((r >> 1) & 3);
        GLOAD_LDS16(Z + (size_t)(bcol + r) * DIM + kt * 64 + lc * 16,
                    lds + bufoff + 16384 + cb * 16);
      }
    };
    auto ld16 = [&](int bufoff, int opoff, int row) -> i64x2 {
      return *(const i64x2*)(lds + bufoff + opoff + row * 64
                             + ((kgrp ^ ((row >> 1) & 3)) << 4));
    };

    i64x2 pa[4], pb[4], qa[4], qb[4];
    f32x4 acc[4][4];
    #pragma unroll
    for (int i = 0; i < 4; ++i)
      #pragma unroll
      for (int j = 0; j < 4; ++j) acc[i][j] = (f32x4){0.f, 0.f, 0.f, 0.f};

#define READF(A_, B_, BO)                                              \
  { _Pragma("unroll") for (int mi = 0; mi < 4; ++mi)                   \
      A_[mi] = ld16((BO), 0, wm * 64 + mi * 16 + lrow);                \
    _Pragma("unroll") for (int ni = 0; ni < 4; ++ni)                   \
      B_[ni] = ld16((BO), 16384, wn * 64 + ni * 16 + lrow); }
#define MMF(A_, B_)                                                    \
  { __builtin_amdgcn_s_setprio(1);                                     \
    _Pragma("unroll") for (int mi = 0; mi < 4; ++mi)                   \
    _Pragma("unroll") for (int ni = 0; ni < 4; ++ni)                   \
      acc[mi][ni] = MFMA_FP8(A_[mi].x, B_[ni].x, acc[mi][ni]);         \
    _Pragma("unroll") for (int mi = 0; mi < 4; ++mi)                   \
    _Pragma("unroll") for (int ni = 0; ni < 4; ++ni)                   \
      acc[mi][ni] = MFMA_FP8(A_[mi].y, B_[ni].y, acc[mi][ni]);         \
    __builtin_amdgcn_s_setprio(0); }

    int oA = 0, oB = 24576, oC = 49152;   // rotating buffer byte offsets
    stage_tile(0, oA);
    stage_tile(1, oB);
    WAIT_VM(0);
    __syncthreads();
    READF(pa, pb, oA);

    for (int I = 0; I < 8; ++I) {
      const int j = 2 * I;
      // ---- even half: MFMA(j) from P, read frags(j+1) into Q ----
      WAIT_VM(0);
      BARRIER();
      READF(qa, qb, oB);
      if (j + 2 < NKT) stage_tile(j + 2, oC);
      MMF(pa, pb);
      { const int tmp = oA; oA = oB; oB = oC; oC = tmp; }
      // ---- odd half: MFMA(j+1) from Q, read frags(j+2) into P ----
      WAIT_VM(0);
      BARRIER();
      if (j + 2 < NKT) READF(pa, pb, oB);
      if (j + 3 < NKT) stage_tile(j + 3, oC);
      MMF(qa, qb);
      { const int tmp = oA; oA = oB; oB = oC; oC = tmp; }
    }
#undef READF
#undef MMF

    // Epilogue. C/D layout (m89): col = lane&15, row = (lane>>4)*4 + j.
    #pragma unroll
    for (int mi = 0; mi < 4; ++mi)
      #pragma unroll
      for (int ni = 0; ni < 4; ++ni)
        #pragma unroll
        for (int j = 0; j < 4; ++j)
          acc[mi][ni][j] = __expf((acc[mi][ni][j] - 1.0f) * INV_T);
    #pragma unroll
    for (int mi = 0; mi < 4; ++mi) {
      float rs[4] = {0.f, 0.f, 0.f, 0.f};
      #pragma unroll
      for (int ni = 0; ni < 4; ++ni)
        #pragma unroll
        for (int j = 0; j < 4; ++j) rs[j] += acc[mi][ni][j];
      #pragma unroll
      for (int j = 0; j < 4; ++j) {
        float s = rs[j];
        s += __shfl_xor(s, 1);
        s += __shfl_xor(s, 2);
        s += __shfl_xor(s, 4);
        s += __shfl_xor(s, 8);
        if (lrow == 0)
          atomicAdd(&rowsum[brow + wm * 64 + mi * 16 + kgrp * 4 + j], s);
      }
    }
    #pragma unroll
    for (int ni = 0; ni < 4; ++ni) {
      float cs = 0.f;
      #pragma unroll
      for (int mi = 0; mi < 4; ++mi)
        cs += acc[mi][ni][0] + acc[mi][ni][1] + acc[mi][ni][2] + acc[mi][ni][3];
      cs += __shfl_xor(cs, 16);
      cs += __shfl_xor(cs, 32);
      if (kgrp == 0)
        atomicAdd(&rowsum[bcol + wn * 64 + ni * 16 + lrow], cs);
    }
  } else {
    // ============================ diag-band tail ============================
    // 96 blocks of 128x128: b2 = 3d + ty; ty0 = upper-tri (r0,c0),
    // ty1 = full (r0,c1), ty2 = lower-tri of (r1,c1). gcol>grow masks all.
    const int b2 = blockIdx.x - NMAIN;
    const int d  = b2 / 3, ty = b2 - d * 3;
    const int arow0 = d * 256 + (ty == 2 ? 128 : 0);
    const int bcol0 = d * 256 + (ty >= 1 ? 128 : 0);
    const int wm = wid >> 2;        // 0..1: 64-row half of 128 rows
    const int wn = wid & 3;         // 0..3: 32-col quarter of 128 cols

    auto stage = [&](int kt, int buf, int rowbase, int opoff) {
      const int cb = wid * 64;      // 512 chunks -> 1 gload/thread
      const int c  = cb + lane;
      const int r  = c >> 2;
      const int lc = (c & 3) ^ ((r >> 1) & 3);
      GLOAD_LDS16(Z + (size_t)(rowbase + r) * DIM + kt * 64 + lc * 16,
                  lds + buf * 16384 + opoff + cb * 16);
    };
    auto ld16 = [&](int buf, int opoff, int row) -> i64x2 {
      return *(const i64x2*)(lds + buf * 16384 + opoff + row * 64
                             + ((kgrp ^ ((row >> 1) & 3)) << 4));
    };

    f32x4 acc[4][2];
    #pragma unroll
    for (int i = 0; i < 4; ++i)
      #pragma unroll
      for (int j = 0; j < 2; ++j) acc[i][j] = (f32x4){0.f, 0.f, 0.f, 0.f};

    stage(0, 0, arow0, 0); stage(0, 0, bcol0, 8192);
    stage(1, 1, arow0, 0); stage(1, 1, bcol0, 8192);
    WAIT_VM(2);
    __builtin_amdgcn_s_barrier();

    int bcur = 0, bnext = 1, bfree = 2;
    for (int kt = 0; kt < NKT; ++kt) {
      i64x2 a[4], b[2];
      #pragma unroll
      for (int mi = 0; mi < 4; ++mi)
        a[mi] = ld16(bcur, 0, wm * 64 + mi * 16 + lrow);
      #pragma unroll
      for (int ni = 0; ni < 2; ++ni)
        b[ni] = ld16(bcur, 8192, wn * 32 + ni * 16 + lrow);
      if (kt + 2 < NKT) {
        stage(kt + 2, bfree, arow0, 0);
        stage(kt + 2, bfree, bcol0, 8192);
      }
      asm volatile("s_waitcnt lgkmcnt(0)" ::: "memory");
      __builtin_amdgcn_sched_barrier(0);
      __builtin_amdgcn_s_setprio(1);
      #pragma unroll
      for (int mi = 0; mi < 4; ++mi)
        #pragma unroll
        for (int ni = 0; ni < 2; ++ni)
          acc[mi][ni] = MFMA_FP8(a[mi].x, b[ni].x, acc[mi][ni]);
      #pragma unroll
      for (int mi = 0; mi < 4; ++mi)
        #pragma unroll
        for (int ni = 0; ni < 2; ++ni)
          acc[mi][ni] = MFMA_FP8(a[mi].y, b[ni].y, acc[mi][ni]);
      __builtin_amdgcn_s_setprio(0);
      if (kt + 2 < NKT) { WAIT_VM(2); }
      else if (kt + 1 < NKT) { WAIT_VM(0); }
      __builtin_amdgcn_s_barrier();
      const int tmp = bcur; bcur = bnext; bnext = bfree; bfree = tmp;
    }

    // Keep only gcol > grow (full cells satisfy it everywhere).
    #pragma unroll
    for (int mi = 0; mi < 4; ++mi)
      #pragma unroll
      for (int ni = 0; ni < 2; ++ni) {
        const int gcol = bcol0 + wn * 32 + ni * 16 + lrow;
        #pragma unroll
        for (int j = 0; j < 4; ++j) {
          const int grow = arow0 + wm * 64 + mi * 16 + kgrp * 4 + j;
          const float v = acc[mi][ni][j];
          acc[mi][ni][j] = (gcol > grow) ? __expf((v - 1.0f) * INV_T) : 0.f;
        }
      }
    #pragma unroll
    for (int mi = 0; mi < 4; ++mi) {
      float rs[4] = {0.f, 0.f, 0.f, 0.f};
      #pragma unroll
      for (int ni = 0; ni < 2; ++ni)
        #pragma unroll
        for (int j = 0; j < 4; ++j) rs[j] += acc[mi][ni][j];
      #pragma unroll
      for (int j = 0; j < 4; ++j) {
        float s = rs[j];
        s += __shfl_xor(s, 1);
        s += __shfl_xor(s, 2);
        s += __shfl_xor(s, 4);
        s += __shfl_xor(s, 8);
        if (lrow == 0)
          atomicAdd(&rowsum[arow0 + wm * 64 + mi * 16 + kgrp * 4 + j], s);
      }
    }
    #pragma unroll
    for (int ni = 0; ni < 2; ++ni) {
      float cs = 0.f;
      #pragma unroll
      for (int mi = 0; mi < 4; ++mi)
        cs += acc[mi][ni][0] + acc[mi][ni][1] + acc[mi][ni][2] + acc[mi][ni][3];
      cs += __shfl_xor(cs, 16);
      cs += __shfl_xor(cs, 32);
      if (kgrp == 0)
        atomicAdd(&rowsum[bcol0 + wn * 32 + ni * 16 + lrow], cs);
    }
  }
}

// ---------------------------------------------------------------------------
// Kernel C: loss = 1/T + mean(log rowsum) - mean(pos)
// ---------------------------------------------------------------------------
__global__ __launch_bounds__(1024) void finalize_kernel(
    const float* __restrict__ rowsum, const float* __restrict__ pos,
    float* __restrict__ out) {
  const int t = threadIdx.x;
  float ls = 0.f, ps = 0.f;
  for (int i = t; i < NROWS; i += 1024) ls += logf(rowsum[i]);
  for (int i = t; i < NPAIR; i += 1024) ps += pos[i];
  #pragma unroll
  for (int off = 32; off; off >>= 1) {
    ls += __shfl_down(ls, off);
    ps += __shfl_down(ps, off);
  }
  __shared__ float sls[16], sps[16];
  const int wave = t >> 6, lane = t & 63;
  if (lane == 0) { sls[wave] = ls; sps[wave] = ps; }
  __syncthreads();
  if (t == 0) {
    float LS = 0.f, PS = 0.f;
    #pragma unroll
    for (int w = 0; w < 16; ++w) { LS += sls[w]; PS += sps[w]; }
    out[0] = INV_T + LS / (float)NROWS - PS / (float)NPAIR;
  }
}

extern "C" void kernel_launch(void* const* d_in, const int* in_sizes, int n_in,
                              void* d_out, int out_size, void* d_ws, size_t ws_size,
                              hipStream_t stream) {
  const float* l1 = (const float*)d_in[0];
  const float* l2 = (const float*)d_in[1];
  float* out = (float*)d_out;

  char* ws = (char*)d_ws;
  unsigned char* Z = (unsigned char*)ws;                   // 8 MB fp8 (k-paired)
  float* rowsum = (float*)(ws + (size_t)NROWS * DIM);      // 32 KB
  float* pos    = rowsum + NROWS;                          // 16 KB

  normalize_kernel<<<NPAIR, 256, 0, stream>>>(l1, l2, Z, pos, rowsum);
  ntxent_gemm_all<<<NMAIN + NTAIL, 512, 0, stream>>>(Z, rowsum);
  finalize_kernel<<<1, 1024, 0, stream>>>(rowsum, pos, out);
}

// Round 15
// 73.957 us; speedup vs baseline: 3.4337x; 3.4337x over previous
//
#include <hip/hip_runtime.h>
#include <hip/hip_bf16.h>

// NT-Xent loss. N=4096 pairs, D=1024, 2N=8192 rows.
// loss = 1/T + mean_i log( sum_{j != i} exp(sim_ij - 1/T) ) - mean_i pos_i
// sim = Z Z^T (cosine); fixed max 1/T (cosine bound) -> no online max.
// R12/R13 (1 blk/CU, 256-reg budget): reg-pipelined P/Q, 91.0 us.
// R14: 2 blk/CU attempt spilled -- (512,4) halves the UNIFIED budget to 128
//      and AGPR acc counts against it: 64 acc + 64 P/Q frags + addr > 128.
// R15: same 2-blk/CU geometry, single frag set (drop ping-pong):
//      64 AGPR + 32 VGPR frags + ~24 addr <= 128. m114 hypothesis:
//      inter-block overlap substitutes for intra-wave pipelining.

#define NPAIR 4096
#define NROWS 8192
#define DIM   1024
#define NMAIN 992                   // 256x128 cells fully above diagonal
#define NTAIL 96                    // diag band: 32 d-blocks x 3 subcells
#define NKT   16                    // K-tiles of 64
#define INV_T 14.285714285714286f   // 1/0.07

typedef __attribute__((ext_vector_type(4))) float f32x4;
typedef __attribute__((ext_vector_type(2))) long  i64x2;

#define GLOAD_LDS16(g, l)                                              \
  __builtin_amdgcn_global_load_lds(                                    \
      (const __attribute__((address_space(1))) void*)(g),              \
      (__attribute__((address_space(3))) void*)(l), 16, 0, 0)

#define MFMA_FP8(A, B, C)                                              \
  __builtin_amdgcn_mfma_f32_16x16x32_fp8_fp8((long)(A), (long)(B), (C), 0, 0, 0)

#define WAIT_VM(N)  asm volatile("s_waitcnt vmcnt(" #N ")" ::: "memory")

// ---------------------------------------------------------------------------
// Kernel A: per pair-row i: norms + cross dot (fp32); write fp8 e4m3
// normalized rows in k-PAIRED layout (16B chunk g = 8B of k-half0 ++ 8B of
// k-half1 within each 64-k tile); pos[i] = cos/T; zero rowsum (2/block).
// ---------------------------------------------------------------------------
__global__ __launch_bounds__(256) void normalize_kernel(
    const float* __restrict__ l1, const float* __restrict__ l2,
    unsigned char* __restrict__ Z, float* __restrict__ pos,
    float* __restrict__ rowsum) {
  const int i = blockIdx.x;
  const int t = threadIdx.x;           // one float4 per thread
  if (t < 2) rowsum[i * 2 + t] = 0.f;
  const float4 a = ((const float4*)(l1 + (size_t)i * DIM))[t];
  const float4 b = ((const float4*)(l2 + (size_t)i * DIM))[t];
  float s1 = a.x*a.x + a.y*a.y + a.z*a.z + a.w*a.w;
  float s2 = b.x*b.x + b.y*b.y + b.z*b.z + b.w*b.w;
  float d  = a.x*b.x + a.y*b.y + a.z*b.z + a.w*b.w;

  #pragma unroll
  for (int off = 32; off; off >>= 1) {
    s1 += __shfl_down(s1, off);
    s2 += __shfl_down(s2, off);
    d  += __shfl_down(d,  off);
  }
  __shared__ float red[3][4];
  __shared__ float fin[3];
  const int wave = t >> 6, lane = t & 63;
  if (lane == 0) { red[0][wave] = s1; red[1][wave] = s2; red[2][wave] = d; }
  __syncthreads();
  if (t == 0) {
    float S1 = red[0][0] + red[0][1] + red[0][2] + red[0][3];
    float S2 = red[1][0] + red[1][1] + red[1][2] + red[1][3];
    float DD = red[2][0] + red[2][1] + red[2][2] + red[2][3];
    float r1 = rsqrtf(S1), r2 = rsqrtf(S2);
    fin[0] = r1; fin[1] = r2;
    pos[i] = DD * r1 * r2 * INV_T;
  }
  __syncthreads();
  const float r1 = fin[0], r2 = fin[1];
  int pa = __builtin_amdgcn_cvt_pk_fp8_f32(a.x * r1, a.y * r1, 0, false);
  pa     = __builtin_amdgcn_cvt_pk_fp8_f32(a.z * r1, a.w * r1, pa, true);
  int pb = __builtin_amdgcn_cvt_pk_fp8_f32(b.x * r2, b.y * r2, 0, false);
  pb     = __builtin_amdgcn_cvt_pk_fp8_f32(b.z * r2, b.w * r2, pb, true);
  const int k0 = t * 4;
  const int noff = (k0 >> 6) * 64 + (((k0 >> 3) & 3) << 4)
                 + (((k0 >> 5) & 1) << 3) + (k0 & 7);
  *(int*)(Z + (size_t)i * DIM + noff) = pa;
  *(int*)(Z + (size_t)(i + NPAIR) * DIM + noff) = pb;
}

// ---------------------------------------------------------------------------
// Kernel B: single dispatch, 1088 blocks, 72 KB LDS -> 2 blocks/CU.
//  blocks [0,992): 256x128 cells fully above the diagonal (bj >= 2bi+2),
//    fp8, single frag set, 3-buffer 2-deep prefetch, counted vmcnt(3),
//    1 barrier/K-tile.
//  blocks [992,1088): diag-band tail, 128x128 cells (gcol>grow mask).
// ---------------------------------------------------------------------------
__global__ __launch_bounds__(512, 4) void ntxent_gemm_all(
    const unsigned char* __restrict__ Z, float* __restrict__ rowsum) {
  __shared__ unsigned char lds[3 * 24576];   // main: 3 bufs x (A 16K + B 8K)

  const int t    = threadIdx.x;
  const int wid  = t >> 6;
  const int lane = t & 63;
  const int lrow = lane & 15;
  const int kgrp = lane >> 4;

  if (blockIdx.x < NMAIN) {
    // =========================== main path (256x128) =======================
    const int wm = wid >> 1;        // 0..3: 64-row quarter of 256 rows
    const int wn = wid & 1;         // 0..1: 64-col half of 128 cols

    // T1: bijective XCD swizzle (992 = 8*124) + decode (R8-verified).
    const int idx = (blockIdx.x & 7) * 124 + (blockIdx.x >> 3);
    int bi = (int)((63.0f - sqrtf(3969.0f - 4.0f * (float)idx)) * 0.5f);
    while ((bi + 1) * (62 - bi) <= idx) ++bi;
    while (bi * (63 - bi) > idx) --bi;
    const int bj = 2 * bi + 2 + (idx - bi * (63 - bi));
    const int brow = bi * 256, bcol = bj * 128;

    // Stage one K-tile: A 256x64 (2 gloads) + B 128x64 (1 gload).
    auto stage_tile = [&](int kt, int bufoff) {
      #pragma unroll
      for (int i = 0; i < 2; ++i) {
        const int cb = wid * 128 + i * 64;   // wave-uniform chunk base
        const int c  = cb + lane;
        const int r  = c >> 2;
        const int lc = (c & 3) ^ ((r >> 1) & 3);
        GLOAD_LDS16(Z + (size_t)(brow + r) * DIM + kt * 64 + lc * 16,
                    lds + bufoff + cb * 16);
      }
      {
        const int cb = wid * 64;
        const int c  = cb + lane;
        const int r  = c >> 2;
        const int lc = (c & 3) ^ ((r >> 1) & 3);
        GLOAD_LDS16(Z + (size_t)(bcol + r) * DIM + kt * 64 + lc * 16,
                    lds + bufoff + 16384 + cb * 16);
      }
    };
    auto ld16 = [&](int bufoff, int opoff, int row) -> i64x2 {
      return *(const i64x2*)(lds + bufoff + opoff + row * 64
                             + ((kgrp ^ ((row >> 1) & 3)) << 4));
    };

    f32x4 acc[4][4];
    #pragma unroll
    for (int i = 0; i < 4; ++i)
      #pragma unroll
      for (int j = 0; j < 4; ++j) acc[i][j] = (f32x4){0.f, 0.f, 0.f, 0.f};

    // Prologue: stage tiles 0,1 (3 gloads each); drain tile 0 -> vmcnt(3).
    stage_tile(0, 0);
    stage_tile(1, 24576);
    WAIT_VM(3);
    __syncthreads();

    int oA = 0, oB = 24576, oC = 49152;   // rotating buffer byte offsets
    for (int kt = 0; kt < NKT; ++kt) {
      i64x2 a[4], b[4];
      #pragma unroll
      for (int mi = 0; mi < 4; ++mi)
        a[mi] = ld16(oA, 0, wm * 64 + mi * 16 + lrow);
      #pragma unroll
      for (int ni = 0; ni < 4; ++ni)
        b[ni] = ld16(oA, 16384, wn * 64 + ni * 16 + lrow);
      if (kt + 2 < NKT) stage_tile(kt + 2, oC);
      asm volatile("s_waitcnt lgkmcnt(0)" ::: "memory");
      __builtin_amdgcn_sched_barrier(0);
      __builtin_amdgcn_s_setprio(1);
      #pragma unroll
      for (int mi = 0; mi < 4; ++mi)
        #pragma unroll
        for (int ni = 0; ni < 4; ++ni)
          acc[mi][ni] = MFMA_FP8(a[mi].x, b[ni].x, acc[mi][ni]);
      #pragma unroll
      for (int mi = 0; mi < 4; ++mi)
        #pragma unroll
        for (int ni = 0; ni < 4; ++ni)
          acc[mi][ni] = MFMA_FP8(a[mi].y, b[ni].y, acc[mi][ni]);
      __builtin_amdgcn_s_setprio(0);
      if (kt + 2 < NKT) { WAIT_VM(3); }      // tile kt+1 landed
      else if (kt + 1 < NKT) { WAIT_VM(0); } // last tile
      __builtin_amdgcn_s_barrier();
      const int tmp = oA; oA = oB; oB = oC; oC = tmp;
    }

    // Epilogue. C/D layout (m89): col = lane&15, row = (lane>>4)*4 + j.
    #pragma unroll
    for (int mi = 0; mi < 4; ++mi)
      #pragma unroll
      for (int ni = 0; ni < 4; ++ni)
        #pragma unroll
        for (int j = 0; j < 4; ++j)
          acc[mi][ni][j] = __expf((acc[mi][ni][j] - 1.0f) * INV_T);
    #pragma unroll
    for (int mi = 0; mi < 4; ++mi) {
      float rs[4] = {0.f, 0.f, 0.f, 0.f};
      #pragma unroll
      for (int ni = 0; ni < 4; ++ni)
        #pragma unroll
        for (int j = 0; j < 4; ++j) rs[j] += acc[mi][ni][j];
      #pragma unroll
      for (int j = 0; j < 4; ++j) {
        float s = rs[j];
        s += __shfl_xor(s, 1);
        s += __shfl_xor(s, 2);
        s += __shfl_xor(s, 4);
        s += __shfl_xor(s, 8);
        if (lrow == 0)
          atomicAdd(&rowsum[brow + wm * 64 + mi * 16 + kgrp * 4 + j], s);
      }
    }
    #pragma unroll
    for (int ni = 0; ni < 4; ++ni) {
      float cs = 0.f;
      #pragma unroll
      for (int mi = 0; mi < 4; ++mi)
        cs += acc[mi][ni][0] + acc[mi][ni][1] + acc[mi][ni][2] + acc[mi][ni][3];
      cs += __shfl_xor(cs, 16);
      cs += __shfl_xor(cs, 32);
      if (kgrp == 0)
        atomicAdd(&rowsum[bcol + wn * 64 + ni * 16 + lrow], cs);
    }
  } else {
    // ============================ diag-band tail ============================
    // 96 blocks of 128x128: b2 = 3d + ty; ty0 = upper-tri (r0,c0),
    // ty1 = full (r0,c1), ty2 = lower-tri of (r1,c1). gcol>grow masks all.
    const int b2 = blockIdx.x - NMAIN;
    const int d  = b2 / 3, ty = b2 - d * 3;
    const int arow0 = d * 256 + (ty == 2 ? 128 : 0);
    const int bcol0 = d * 256 + (ty >= 1 ? 128 : 0);
    const int wm = wid >> 2;        // 0..1: 64-row half of 128 rows
    const int wn = wid & 3;         // 0..3: 32-col quarter of 128 cols

    auto stage = [&](int kt, int buf, int rowbase, int opoff) {
      const int cb = wid * 64;      // 512 chunks -> 1 gload/thread
      const int c  = cb + lane;
      const int r  = c >> 2;
      const int lc = (c & 3) ^ ((r >> 1) & 3);
      GLOAD_LDS16(Z + (size_t)(rowbase + r) * DIM + kt * 64 + lc * 16,
                  lds + buf * 16384 + opoff + cb * 16);
    };
    auto ld16 = [&](int buf, int opoff, int row) -> i64x2 {
      return *(const i64x2*)(lds + buf * 16384 + opoff + row * 64
                             + ((kgrp ^ ((row >> 1) & 3)) << 4));
    };

    f32x4 acc[4][2];
    #pragma unroll
    for (int i = 0; i < 4; ++i)
      #pragma unroll
      for (int j = 0; j < 2; ++j) acc[i][j] = (f32x4){0.f, 0.f, 0.f, 0.f};

    stage(0, 0, arow0, 0); stage(0, 0, bcol0, 8192);
    stage(1, 1, arow0, 0); stage(1, 1, bcol0, 8192);
    WAIT_VM(2);
    __builtin_amdgcn_s_barrier();

    int bcur = 0, bnext = 1, bfree = 2;
    for (int kt = 0; kt < NKT; ++kt) {
      i64x2 a[4], b[2];
      #pragma unroll
      for (int mi = 0; mi < 4; ++mi)
        a[mi] = ld16(bcur, 0, wm * 64 + mi * 16 + lrow);
      #pragma unroll
      for (int ni = 0; ni < 2; ++ni)
        b[ni] = ld16(bcur, 8192, wn * 32 + ni * 16 + lrow);
      if (kt + 2 < NKT) {
        stage(kt + 2, bfree, arow0, 0);
        stage(kt + 2, bfree, bcol0, 8192);
      }
      asm volatile("s_waitcnt lgkmcnt(0)" ::: "memory");
      __builtin_amdgcn_sched_barrier(0);
      __builtin_amdgcn_s_setprio(1);
      #pragma unroll
      for (int mi = 0; mi < 4; ++mi)
        #pragma unroll
        for (int ni = 0; ni < 2; ++ni)
          acc[mi][ni] = MFMA_FP8(a[mi].x, b[ni].x, acc[mi][ni]);
      #pragma unroll
      for (int mi = 0; mi < 4; ++mi)
        #pragma unroll
        for (int ni = 0; ni < 2; ++ni)
          acc[mi][ni] = MFMA_FP8(a[mi].y, b[ni].y, acc[mi][ni]);
      __builtin_amdgcn_s_setprio(0);
      if (kt + 2 < NKT) { WAIT_VM(2); }
      else if (kt + 1 < NKT) { WAIT_VM(0); }
      __builtin_amdgcn_s_barrier();
      const int tmp = bcur; bcur = bnext; bnext = bfree; bfree = tmp;
    }

    // Keep only gcol > grow (full cells satisfy it everywhere).
    #pragma unroll
    for (int mi = 0; mi < 4; ++mi)
      #pragma unroll
      for (int ni = 0; ni < 2; ++ni) {
        const int gcol = bcol0 + wn * 32 + ni * 16 + lrow;
        #pragma unroll
        for (int j = 0; j < 4; ++j) {
          const int grow = arow0 + wm * 64 + mi * 16 + kgrp * 4 + j;
          const float v = acc[mi][ni][j];
          acc[mi][ni][j] = (gcol > grow) ? __expf((v - 1.0f) * INV_T) : 0.f;
        }
      }
    #pragma unroll
    for (int mi = 0; mi < 4; ++mi) {
      float rs[4] = {0.f, 0.f, 0.f, 0.f};
      #pragma unroll
      for (int ni = 0; ni < 2; ++ni)
        #pragma unroll
        for (int j = 0; j < 4; ++j) rs[j] += acc[mi][ni][j];
      #pragma unroll
      for (int j = 0; j < 4; ++j) {
        float s = rs[j];
        s += __shfl_xor(s, 1);
        s += __shfl_xor(s, 2);
        s += __shfl_xor(s, 4);
        s += __shfl_xor(s, 8);
        if (lrow == 0)
          atomicAdd(&rowsum[arow0 + wm * 64 + mi * 16 + kgrp * 4 + j], s);
      }
    }
    #pragma unroll
    for (int ni = 0; ni < 2; ++ni) {
      float cs = 0.f;
      #pragma unroll
      for (int mi = 0; mi < 4; ++mi)
        cs += acc[mi][ni][0] + acc[mi][ni][1] + acc[mi][ni][2] + acc[mi][ni][3];
      cs += __shfl_xor(cs, 16);
      cs += __shfl_xor(cs, 32);
      if (kgrp == 0)
        atomicAdd(&rowsum[bcol0 + wn * 32 + ni * 16 + lrow], cs);
    }
  }
}

// ---------------------------------------------------------------------------
// Kernel C: loss = 1/T + mean(log rowsum) - mean(pos)
// ---------------------------------------------------------------------------
__global__ __launch_bounds__(1024) void finalize_kernel(
    const float* __restrict__ rowsum, const float* __restrict__ pos,
    float* __restrict__ out) {
  const int t = threadIdx.x;
  float ls = 0.f, ps = 0.f;
  for (int i = t; i < NROWS; i += 1024) ls += logf(rowsum[i]);
  for (int i = t; i < NPAIR; i += 1024) ps += pos[i];
  #pragma unroll
  for (int off = 32; off; off >>= 1) {
    ls += __shfl_down(ls, off);
    ps += __shfl_down(ps, off);
  }
  __shared__ float sls[16], sps[16];
  const int wave = t >> 6, lane = t & 63;
  if (lane == 0) { sls[wave] = ls; sps[wave] = ps; }
  __syncthreads();
  if (t == 0) {
    float LS = 0.f, PS = 0.f;
    #pragma unroll
    for (int w = 0; w < 16; ++w) { LS += sls[w]; PS += sps[w]; }
    out[0] = INV_T + LS / (float)NROWS - PS / (float)NPAIR;
  }
}

extern "C" void kernel_launch(void* const* d_in, const int* in_sizes, int n_in,
                              void* d_out, int out_size, void* d_ws, size_t ws_size,
                              hipStream_t stream) {
  const float* l1 = (const float*)d_in[0];
  const float* l2 = (const float*)d_in[1];
  float* out = (float*)d_out;

  char* ws = (char*)d_ws;
  unsigned char* Z = (unsigned char*)ws;                   // 8 MB fp8 (k-paired)
  float* rowsum = (float*)(ws + (size_t)NROWS * DIM);      // 32 KB
  float* pos    = rowsum + NROWS;                          // 16 KB

  normalize_kernel<<<NPAIR, 256, 0, stream>>>(l1, l2, Z, pos, rowsum);
  ntxent_gemm_all<<<NMAIN + NTAIL, 512, 0, stream>>>(Z, rowsum);
  finalize_kernel<<<1, 1024, 0, stream>>>(rowsum, pos, out);
}